// Round 7
// baseline (332.681 us; speedup 1.0000x reference)
//
#include <hip/hip_runtime.h>

// MultiRelGraphTransformer on MI355X — round 7.
// vs r6: gemm_ln and proj epilogues vectorized via LDS repack (r6 used 2-byte
// scalar global loads/stores for residual + output — wave-width 32 B
// transactions). K-loop and spmm unchanged (spmm near structural floor:
// 491 MB logical gather, L2 absorbs 75%, capacity-miss bound).

#define NNODES 20000
#define NB     4
#define BROWS  (NB * NNODES)   // 80000
#define DN     64
#define DM     128
#define NE     160000
#define CAP    64              // bucket capacity per (relation,dst); Poisson(8)
#define LN_EPS 1e-5f
#define KE     448             // 384 spmm cols + 64 ext cols
#define LDW    88              // K-loop LDS row stride (ushorts): 44 dw -> 2-way free
#define HTW    132             // residual tile stride (ushorts)
#define FOW    132             // f32 out tile stride (floats), 528 B: 16B-mult
#define UOW    136             // bf16 out tile stride (ushorts), 272 B: 16B-mult

typedef __attribute__((ext_vector_type(8))) short bf16x8;
typedef __attribute__((ext_vector_type(4))) float f32x4;

__device__ inline float bf2f(unsigned short u) {
    union { unsigned int i; float f; } x; x.i = ((unsigned int)u) << 16; return x.f;
}
__device__ inline unsigned short f2bf(float f) {
    union { float f; unsigned int i; } x; x.f = f;
    unsigned int r = x.i + 0x7FFFu + ((x.i >> 16) & 1u);
    return (unsigned short)(r >> 16);
}

// ---------- K1: counting-sort into fixed buckets (cursor = true degree) ----------
__global__ void k_scatter(const int* __restrict__ ei0, const int* __restrict__ ei1,
                          const int* __restrict__ ei2, int* __restrict__ cursor,
                          int* __restrict__ srcs, int* __restrict__ eids) {
    int tid = blockIdx.x * blockDim.x + threadIdx.x;
    if (tid >= 3 * NE) return;
    int r = tid / NE, e = tid - r * NE;
    const int* ei = (r == 0) ? ei0 : ((r == 1) ? ei1 : ei2);
    int src = ei[e], dst = ei[NE + e];
    int p = atomicAdd(&cursor[r * NNODES + dst], 1);
    if (p < CAP) {
        srcs[(r * NNODES + dst) * CAP + p] = src;
        if (r < 2) eids[(r * NNODES + dst) * CAP + p] = e;
    }
}

// ---------- K2: S[r][n][16] = sum of ea_r over incoming edges (bucket walk) ----------
__global__ __launch_bounds__(256) void k_sgather(const int* __restrict__ deg,
                                                 const int* __restrict__ eids,
                                                 const float* __restrict__ ea0,
                                                 const float* __restrict__ ea1,
                                                 float* __restrict__ S) {
    int task = blockIdx.x * 4 + (threadIdx.x >> 6);   // 0 .. 2*NNODES-1
    int r = task / NNODES;
    const float* ea = r ? ea1 : ea0;
    int lane = threadIdx.x & 63;
    int k = lane & 15, sub = lane >> 4;
    int dg = deg[task]; if (dg > CAP) dg = CAP;
    const int* bk = eids + (size_t)task * CAP;
    float acc = 0.f;
    for (int j = sub; j < dg; j += 4) {
        int e = bk[j];
        acc += ea[e * 16 + k];
    }
    acc += __shfl_xor(acc, 16, 64);
    acc += __shfl_xor(acc, 32, 64);
    if (lane < 16) S[(size_t)task * 16 + k] = acc;
}

// ---------- K3: build Wt[2][128][448] (transposed node_W + ext rows) and Wp[128][64] ----------
__global__ __launch_bounds__(256) void k_wprep(const float* __restrict__ nW,
                                               const float* __restrict__ nb,
                                               const float* __restrict__ eW,
                                               const float* __restrict__ eb,
                                               const float* __restrict__ inW,
                                               unsigned short* __restrict__ Wt,
                                               unsigned short* __restrict__ Wp) {
    int lin = blockIdx.x * 256 + threadIdx.x;    // 2*128*448 + 128*64 = 122880
    if (lin < 2 * 128 * KE) {
        int l = lin / (128 * KE);
        int rem = lin - l * 128 * KE;
        int n = rem / KE, k = rem - n * KE;
        float v;
        if (k < 384) {
            int r = k >> 7, kk = k & 127;
            v = nW[(((size_t)(l * 3 + r) * 128) + kk) * 128 + n];
        } else {
            int e = k - 384;
            if (e < 3) {
                v = nb[(l * 3 + e) * DM + n];
                if (e < 2) v += eb[(l * 2 + e) * DM + n];
            } else if (e < 35) {
                int r2 = (e - 3) >> 4, j = (e - 3) & 15;
                v = eW[((size_t)((l * 2 + r2) * 16 + j)) * DM + n];
            } else v = 0.f;
        }
        Wt[lin] = f2bf(v);
    } else {
        int i = lin - 2 * 128 * KE;
        int n = i >> 6, k = i & 63;
        Wp[n * 64 + k] = f2bf(inW[(size_t)k * DM + n]);
    }
}

// ---------- K4: input projection HB = bf16(node_feat @ in_W + in_b), MFMA ----------
__global__ __launch_bounds__(256) void k_proj(const float* __restrict__ X,
                                              const unsigned short* __restrict__ Wp,  // [128][64]
                                              const float* __restrict__ bias,
                                              unsigned short* __restrict__ HB) {
    __shared__ __align__(16) unsigned char smem[33792];
    unsigned short* As = (unsigned short*)smem;              // [64][LDW]
    unsigned short* Bs = (unsigned short*)(smem + 11264);    // [128][LDW]
    unsigned short* UO = (unsigned short*)smem;              // [64][UOW] (epilogue)
    int t = threadIdx.x;
    int m0 = blockIdx.x * 64;
    // stage A: 64x64 fp32 -> bf16
#pragma unroll
    for (int i = 0; i < 4; ++i) {
        int lin = t + 256 * i;
        int row = lin >> 4, seg = lin & 15;
        float4 v = *(const float4*)(X + (size_t)(m0 + row) * DN + seg * 4);
        ushort4 h; h.x = f2bf(v.x); h.y = f2bf(v.y); h.z = f2bf(v.z); h.w = f2bf(v.w);
        *(ushort4*)&As[row * LDW + seg * 4] = h;
    }
    // stage B: 128x64 bf16
#pragma unroll
    for (int i = 0; i < 4; ++i) {
        int lin = t + 256 * i;
        int row = lin >> 3, seg = lin & 7;
        *(uint4*)&Bs[row * LDW + seg * 8] = *(const uint4*)(Wp + (size_t)row * 64 + seg * 8);
    }
    __syncthreads();
    int w = t >> 6, lane = t & 63;
    int q = lane >> 4, lm = lane & 15;
    f32x4 acc[8];
#pragma unroll
    for (int ct = 0; ct < 8; ++ct) acc[ct] = (f32x4){0.f, 0.f, 0.f, 0.f};
#pragma unroll
    for (int kt = 0; kt < 2; ++kt) {
        bf16x8 a = *(const bf16x8*)&As[(w * 16 + lm) * LDW + kt * 32 + q * 8];
#pragma unroll
        for (int ct = 0; ct < 8; ++ct) {
            bf16x8 bf = *(const bf16x8*)&Bs[(ct * 16 + lm) * LDW + kt * 32 + q * 8];
            acc[ct] = __builtin_amdgcn_mfma_f32_16x16x32_bf16(a, bf, acc[ct], 0, 0, 0);
        }
    }
    __syncthreads();   // As/Bs dead; UO aliases
#pragma unroll
    for (int reg = 0; reg < 4; ++reg) {
        int rl = w * 16 + q * 4 + reg;
#pragma unroll
        for (int ct = 0; ct < 8; ++ct) {
            int col = ct * 16 + lm;
            UO[rl * UOW + col] = f2bf(acc[ct][reg] + bias[col]);
        }
    }
    __syncthreads();
#pragma unroll
    for (int i = 0; i < 4; ++i) {
        int lin = t + 256 * i;            // 64 rows x 16 segs of 8 ushorts
        int row = lin >> 4, seg = lin & 15;
        *(uint4*)(HB + (size_t)(m0 + row) * DM + seg * 8) = *(uint4*)&UO[row * UOW + seg * 8];
    }
}

// ---------- K5: SpMM + ext-col write (unchanged from r6) ----------
__global__ __launch_bounds__(256) void k_spmm(const unsigned short* __restrict__ HB,
                                              const int* __restrict__ deg,
                                              const int* __restrict__ srcs,
                                              const float* __restrict__ S,
                                              unsigned short* __restrict__ G) {
    int blk = blockIdx.x;                      // 5000
    int s = blk & 7;
    int bb = s >> 1;                           // xcd -> batch
    int idx = ((blk >> 3) << 1) + (s & 1);     // [0,1250)
    int n0 = idx * 16;
    int g = threadIdx.x >> 4, lane = threadIdx.x & 15;
    int n = n0 + g;
    int c8 = lane * 8;
    const unsigned short* Hb = HB + (size_t)bb * NNODES * DM;
    size_t rowbase = ((size_t)(bb * NNODES + n)) * KE;
    int dt[3];
#pragma unroll
    for (int r = 0; r < 3; ++r) {
        dt[r] = deg[r * NNODES + n];
        int dg = dt[r] > CAP ? CAP : dt[r];
        const int* bk = srcs + (size_t)(r * NNODES + n) * CAP;
        float a[8];
#pragma unroll
        for (int j = 0; j < 8; ++j) a[j] = 0.f;
        int j = 0;
        for (; j + 3 < dg; j += 4) {
            int4 s4 = *(const int4*)&bk[j];
            ushort4 u0 = *(const ushort4*)(Hb + (size_t)s4.x * DM + c8);
            ushort4 u1 = *(const ushort4*)(Hb + (size_t)s4.x * DM + c8 + 4);
            ushort4 v0 = *(const ushort4*)(Hb + (size_t)s4.y * DM + c8);
            ushort4 v1 = *(const ushort4*)(Hb + (size_t)s4.y * DM + c8 + 4);
            ushort4 w0 = *(const ushort4*)(Hb + (size_t)s4.z * DM + c8);
            ushort4 w1 = *(const ushort4*)(Hb + (size_t)s4.z * DM + c8 + 4);
            ushort4 x0 = *(const ushort4*)(Hb + (size_t)s4.w * DM + c8);
            ushort4 x1 = *(const ushort4*)(Hb + (size_t)s4.w * DM + c8 + 4);
            a[0] += bf2f(u0.x) + bf2f(v0.x) + bf2f(w0.x) + bf2f(x0.x);
            a[1] += bf2f(u0.y) + bf2f(v0.y) + bf2f(w0.y) + bf2f(x0.y);
            a[2] += bf2f(u0.z) + bf2f(v0.z) + bf2f(w0.z) + bf2f(x0.z);
            a[3] += bf2f(u0.w) + bf2f(v0.w) + bf2f(w0.w) + bf2f(x0.w);
            a[4] += bf2f(u1.x) + bf2f(v1.x) + bf2f(w1.x) + bf2f(x1.x);
            a[5] += bf2f(u1.y) + bf2f(v1.y) + bf2f(w1.y) + bf2f(x1.y);
            a[6] += bf2f(u1.z) + bf2f(v1.z) + bf2f(w1.z) + bf2f(x1.z);
            a[7] += bf2f(u1.w) + bf2f(v1.w) + bf2f(w1.w) + bf2f(x1.w);
        }
        for (; j < dg; ++j) {
            int s0 = bk[j];
            ushort4 u0 = *(const ushort4*)(Hb + (size_t)s0 * DM + c8);
            ushort4 u1 = *(const ushort4*)(Hb + (size_t)s0 * DM + c8 + 4);
            a[0] += bf2f(u0.x); a[1] += bf2f(u0.y); a[2] += bf2f(u0.z); a[3] += bf2f(u0.w);
            a[4] += bf2f(u1.x); a[5] += bf2f(u1.y); a[6] += bf2f(u1.z); a[7] += bf2f(u1.w);
        }
        ushort4 o0, o1;
        o0.x = f2bf(a[0]); o0.y = f2bf(a[1]); o0.z = f2bf(a[2]); o0.w = f2bf(a[3]);
        o1.x = f2bf(a[4]); o1.y = f2bf(a[5]); o1.z = f2bf(a[6]); o1.w = f2bf(a[7]);
        *(ushort4*)(G + rowbase + r * 128 + c8) = o0;
        *(ushort4*)(G + rowbase + r * 128 + c8 + 4) = o1;
    }
    if (lane < 8) {
        ushort4 e0, e1;
        unsigned short ev[8];
#pragma unroll
        for (int j = 0; j < 8; ++j) {
            int kk = lane * 8 + j;
            float v;
            if (kk < 3)       v = (float)dt[kk];
            else if (kk < 19) v = S[((size_t)(0 * NNODES + n)) * 16 + (kk - 3)];
            else if (kk < 35) v = S[((size_t)(1 * NNODES + n)) * 16 + (kk - 19)];
            else              v = 0.f;
            ev[j] = f2bf(v);
        }
        e0.x = ev[0]; e0.y = ev[1]; e0.z = ev[2]; e0.w = ev[3];
        e1.x = ev[4]; e1.y = ev[5]; e1.z = ev[6]; e1.w = ev[7];
        *(ushort4*)(G + rowbase + 384 + lane * 8) = e0;
        *(ushort4*)(G + rowbase + 384 + lane * 8 + 4) = e1;
    }
}

// ---------- K6: bf16 MFMA GEMM [64x448]@[448x128] + residual + ReLU + LN ----------
// Epilogue fully vectorized: HB residual staged to LDS via uint4; LN output
// repacked through LDS and flushed with uint4/float4.
__global__ __launch_bounds__(256) void k_gemm_ln(const unsigned short* __restrict__ G,   // [BROWS][448]
                                                 const unsigned short* __restrict__ Wt,  // [128][448]
                                                 unsigned short* HB,
                                                 const float* __restrict__ lng,
                                                 const float* __restrict__ lnb,
                                                 float* __restrict__ out, int write_f32) {
    __shared__ __align__(16) unsigned char smem[50688];
    unsigned short* Gs = (unsigned short*)smem;              // [64][LDW]   K-loop
    unsigned short* Ws = (unsigned short*)(smem + 11264);    // [128][LDW]  K-loop
    unsigned short* HT = (unsigned short*)smem;              // [64][HTW]   epilogue residual
    float*          FO = (float*)(smem + 16896);             // [64][FOW]   epilogue f32 out
    unsigned short* UO = (unsigned short*)(smem + 16896);    // [64][UOW]   epilogue bf16 out
    int t = threadIdx.x;
    int m0 = blockIdx.x * 64;
    int w = t >> 6, lane = t & 63;
    int q = lane >> 4, lm = lane & 15;

    f32x4 acc[8];
#pragma unroll
    for (int ct = 0; ct < 8; ++ct) acc[ct] = (f32x4){0.f, 0.f, 0.f, 0.f};

    for (int kc = 0; kc < 7; ++kc) {
#pragma unroll
        for (int i = 0; i < 2; ++i) {
            int lin = t + 256 * i;
            int row = lin >> 3, seg = lin & 7;
            *(uint4*)&Gs[row * LDW + seg * 8] =
                *(const uint4*)(G + (size_t)(m0 + row) * KE + kc * 64 + seg * 8);
        }
#pragma unroll
        for (int i = 0; i < 4; ++i) {
            int lin = t + 256 * i;
            int row = lin >> 3, seg = lin & 7;
            *(uint4*)&Ws[row * LDW + seg * 8] =
                *(const uint4*)(Wt + (size_t)row * KE + kc * 64 + seg * 8);
        }
        __syncthreads();
#pragma unroll
        for (int kt = 0; kt < 2; ++kt) {
            bf16x8 a = *(const bf16x8*)&Gs[(w * 16 + lm) * LDW + kt * 32 + q * 8];
#pragma unroll
            for (int ct = 0; ct < 8; ++ct) {
                bf16x8 bf = *(const bf16x8*)&Ws[(ct * 16 + lm) * LDW + kt * 32 + q * 8];
                acc[ct] = __builtin_amdgcn_mfma_f32_16x16x32_bf16(a, bf, acc[ct], 0, 0, 0);
            }
        }
        __syncthreads();
    }

    // stage residual tile (vectorized) into HT — Gs/Ws dead after last sync
#pragma unroll
    for (int i = 0; i < 4; ++i) {
        int lin = t + 256 * i;            // 64 rows x 16 segs of 8 ushorts
        int row = lin >> 4, seg = lin & 15;
        *(uint4*)&HT[row * HTW + seg * 8] = *(const uint4*)(HB + (size_t)(m0 + row) * DM + seg * 8);
    }
    __syncthreads();

    float gc[8], bc[8];
#pragma unroll
    for (int ct = 0; ct < 8; ++ct) {
        int col = ct * 16 + lm;
        gc[ct] = lng[col]; bc[ct] = lnb[col];
    }
#pragma unroll
    for (int reg = 0; reg < 4; ++reg) {
        int rl = w * 16 + q * 4 + reg;
        float xv[8];
        float s1 = 0.f, s2 = 0.f;
#pragma unroll
        for (int ct = 0; ct < 8; ++ct) {
            int col = ct * 16 + lm;
            float h = bf2f(HT[rl * HTW + col]);
            float v = h + fmaxf(acc[ct][reg], 0.f);
            xv[ct] = v; s1 += v; s2 += v * v;
        }
#pragma unroll
        for (int m = 1; m <= 8; m <<= 1) {
            s1 += __shfl_xor(s1, m, 64);
            s2 += __shfl_xor(s2, m, 64);
        }
        float mu  = s1 * (1.f / 128.f);
        float var = s2 * (1.f / 128.f) - mu * mu;
        float inv = rsqrtf(var + LN_EPS);
        if (write_f32) {
#pragma unroll
            for (int ct = 0; ct < 8; ++ct) {
                int col = ct * 16 + lm;
                FO[rl * FOW + col] = (xv[ct] - mu) * inv * gc[ct] + bc[ct];
            }
        } else {
#pragma unroll
            for (int ct = 0; ct < 8; ++ct) {
                int col = ct * 16 + lm;
                UO[rl * UOW + col] = f2bf((xv[ct] - mu) * inv * gc[ct] + bc[ct]);
            }
        }
    }
    __syncthreads();
    if (write_f32) {
#pragma unroll
        for (int i = 0; i < 8; ++i) {
            int lin = t + 256 * i;        // 64 rows x 32 float4-segs
            int row = lin >> 5, seg = lin & 31;
            *(float4*)(out + (size_t)(m0 + row) * DM + seg * 4) = *(float4*)&FO[row * FOW + seg * 4];
        }
    } else {
#pragma unroll
        for (int i = 0; i < 4; ++i) {
            int lin = t + 256 * i;        // 64 rows x 16 segs of 8 ushorts
            int row = lin >> 4, seg = lin & 15;
            *(uint4*)(HB + (size_t)(m0 + row) * DM + seg * 8) = *(uint4*)&UO[row * UOW + seg * 8];
        }
    }
}

extern "C" void kernel_launch(void* const* d_in, const int* in_sizes, int n_in,
                              void* d_out, int out_size, void* d_ws, size_t ws_size,
                              hipStream_t stream) {
    const float* node_feat = (const float*)d_in[0];
    const float* in_W   = (const float*)d_in[1];
    const float* in_b   = (const float*)d_in[2];
    const float* node_W = (const float*)d_in[3];   // [2][3][128][128]
    const float* node_b = (const float*)d_in[4];   // [2][3][128]
    const float* edge_W = (const float*)d_in[5];   // [2][2][16][128]
    const float* edge_b = (const float*)d_in[6];   // [2][2][128]
    const float* ln_g   = (const float*)d_in[7];   // [2][128]
    const float* ln_b   = (const float*)d_in[8];   // [2][128]
    const float* ea0    = (const float*)d_in[9];
    const float* ea1    = (const float*)d_in[10];
    const int*   ei0    = (const int*)d_in[11];
    const int*   ei1    = (const int*)d_in[12];
    const int*   ei2    = (const int*)d_in[13];
    float* out = (float*)d_out;

    char* ws = (char*)d_ws;
    size_t off = 0;
    auto alloc = [&](size_t bytes) -> void* {
        void* p = ws + off;
        off = (off + bytes + 255) & ~(size_t)255;
        return p;
    };
    unsigned short* HB     = (unsigned short*)alloc((size_t)BROWS * DM * 2);   // 20.5 MB
    unsigned short* G      = (unsigned short*)alloc((size_t)BROWS * KE * 2);   // 71.7 MB
    int*            cursor = (int*)alloc((size_t)3 * NNODES * 4);              // zeroed
    float*          S      = (float*)alloc((size_t)2 * NNODES * 16 * 4);
    int*            srcs   = (int*)alloc((size_t)3 * NNODES * CAP * 4);        // 15.4 MB
    int*            eids   = (int*)alloc((size_t)2 * NNODES * CAP * 4);        // 10.2 MB
    unsigned short* Wt     = (unsigned short*)alloc((size_t)2 * 128 * KE * 2);
    unsigned short* Wp     = (unsigned short*)alloc((size_t)128 * 64 * 2);

    hipMemsetAsync(cursor, 0, (size_t)3 * NNODES * 4, stream);

    k_scatter<<<(3 * NE + 255) / 256, 256, 0, stream>>>(ei0, ei1, ei2, cursor, srcs, eids);
    k_sgather<<<(2 * NNODES) / 4, 256, 0, stream>>>(cursor, eids, ea0, ea1, S);
    k_wprep<<<480, 256, 0, stream>>>(node_W, node_b, edge_W, edge_b, in_W, Wt, Wp);
    k_proj<<<BROWS / 64, 256, 0, stream>>>(node_feat, Wp, in_b, HB);

    for (int l = 0; l < 2; ++l) {
        k_spmm<<<5000, 256, 0, stream>>>(HB, cursor, srcs, S, G);
        k_gemm_ln<<<BROWS / 64, 256, 0, stream>>>(G, Wt + (size_t)l * 128 * KE, HB,
                                                  ln_g + (size_t)l * DM, ln_b + (size_t)l * DM,
                                                  out, l == 1);
    }
}